// Round 7
// baseline (143.712 us; speedup 1.0000x reference)
//
#include <hip/hip_runtime.h>

#define SCALE 0.17677669529663687f  // 1/sqrt(32)
#define PSTR 516                    // s_p row stride: mult of 4 (b128), !mult of 32 (banks)

// 64 FMAs: acc[h] += E.[xyzw]*qce + X.[xyzw]*qcx for 4 channels
#define FMA64(E, X, qc)                                                         \
  {                                                                             \
    const float* _q = (qc);                                                     \
    _Pragma("unroll")                                                           \
    for (int h = 0; h < 8; ++h)                                                 \
      acc[h] += (E).x * _q[h]      + (E).y * _q[16 + h]                         \
              + (E).z * _q[32 + h] + (E).w * _q[48 + h]                         \
              + (X).x * _q[8 + h]  + (X).y * _q[24 + h]                         \
              + (X).z * _q[40 + h] + (X).w * _q[56 + h];                        \
  }

// ---------------------------------------------------------------------------
// Single fused kernel: one block per query row i. 512 blocks x 512 thr.
// Prologue: q_s = (x[i]@Wq)*SCALE; coefs qce[c,h] (vs We), qcx[c,h] (vs Wk)
// P1 (thread=j, 8-deep load pipeline): logit[h][j]
// P2: softmax per head (64 lanes/head), normalize in place in s_p
// P3 (lane=c, wave owns 64 j, 8-j batches): ae[h,c], px[h,c]
// Epilogue: emb[nd] = sum_c ae*We + px*Wv; out = emb@Wo + bo
// ---------------------------------------------------------------------------
__global__ __launch_bounds__(512, 4) void fused_kernel(
    const float* __restrict__ e, const float* __restrict__ x,
    const float* __restrict__ Wq, const float* __restrict__ Wk,
    const float* __restrict__ We, const float* __restrict__ Wv,
    const float* __restrict__ Wo, const float* __restrict__ bo,
    float* __restrict__ out) {
  const int t = threadIdx.x, i = blockIdx.x;
  __shared__ float s_x[64];
  __shared__ __align__(16) float s_q[256];
  __shared__ __align__(16) float s_qc[1024];       //  4 KB coefs
  __shared__ __align__(16) float s_p[8 * PSTR];    // 16.1 KB logits/probs
  __shared__ __align__(16) float s_part[8 * 1024]; // 32 KB wave partials (ae|px)
  __shared__ float s_ae[512], s_px[512];
  __shared__ float s_emb[256];
  __shared__ float s_op[8 * 64];

  // ---- Prologue: coefficients
  if (t < 64) s_x[t] = x[i * 64 + t];
  __syncthreads();
  if (t < 256) {
    float a = 0;
#pragma unroll 8
    for (int c = 0; c < 64; ++c) a += s_x[c] * Wq[c * 256 + t];
    s_q[t] = a * SCALE;
  }
  __syncthreads();
  {
    const int c = t >> 3, h = t & 7;
    const float4* wer = (const float4*)(We + c * 256 + h * 32);
    const float4* wkr = (const float4*)(Wk + c * 256 + h * 32);
    const float4* qr = (const float4*)(s_q + h * 32);
    float se = 0, sk = 0;
#pragma unroll
    for (int u = 0; u < 8; ++u) {
      float4 w1 = wer[u], w2 = wkr[u], qv = qr[u];
      se += qv.x * w1.x + qv.y * w1.y + qv.z * w1.z + qv.w * w1.w;
      sk += qv.x * w2.x + qv.y * w2.y + qv.z * w2.z + qv.w * w2.w;
    }
    s_qc[c * 16 + h] = se;
    s_qc[c * 16 + 8 + h] = sk;
  }
  __syncthreads();

  // ---- Phase 1: one j per thread; 8-deep float4 load pipeline
  {
    const int j = t;
    const float4* erow = (const float4*)(e + (size_t)(i * 512 + j) * 64);
    const float4* xrow = (const float4*)(x + j * 64);
    float4 Eb[8], Xb[8];
#pragma unroll
    for (int u = 0; u < 8; ++u) Eb[u] = erow[u];
#pragma unroll
    for (int u = 0; u < 8; ++u) Xb[u] = xrow[u];
    float acc[8];
#pragma unroll
    for (int h = 0; h < 8; ++h) acc[h] = 0.f;
    // half 0: consume chunk u, immediately refill with chunk 8+u
#pragma unroll
    for (int u = 0; u < 8; ++u) {
      FMA64(Eb[u], Xb[u], s_qc + u * 64);
      Eb[u] = erow[8 + u];
      Xb[u] = xrow[8 + u];
    }
    // half 1
#pragma unroll
    for (int u = 0; u < 8; ++u) FMA64(Eb[u], Xb[u], s_qc + (8 + u) * 64);
#pragma unroll
    for (int h = 0; h < 8; ++h) s_p[h * PSTR + j] = acc[h];
  }
  __syncthreads();

  // ---- Phase 2: softmax per head (64 lanes/head); normalize in place
  {
    const int n = t >> 6, l64 = t & 63;
    float m = -1e30f;
#pragma unroll
    for (int u = 0; u < 8; ++u) m = fmaxf(m, s_p[n * PSTR + l64 + u * 64]);
#pragma unroll
    for (int off = 32; off; off >>= 1) m = fmaxf(m, __shfl_xor(m, off, 64));
    float pv[8];
    float sum = 0;
#pragma unroll
    for (int u = 0; u < 8; ++u) {
      pv[u] = __expf(s_p[n * PSTR + l64 + u * 64] - m);
      sum += pv[u];
    }
#pragma unroll
    for (int off = 32; off; off >>= 1) sum += __shfl_xor(sum, off, 64);
    const float inv = 1.0f / sum;
#pragma unroll
    for (int u = 0; u < 8; ++u) s_p[n * PSTR + l64 + u * 64] = pv[u] * inv;
  }
  __syncthreads();

  // ---- Phase 3: lane=c, wave w owns j in [w*64, w*64+64), 8-j batches
  {
    const int lane = t & 63, w = t >> 6;
    float ae[8], px[8];
#pragma unroll
    for (int h = 0; h < 8; ++h) { ae[h] = 0.f; px[h] = 0.f; }
    const float* ep = e + (size_t)i * 32768 + (size_t)w * 4096 + lane;
    const float* xp = x + w * 4096 + lane;
    for (int jb = 0; jb < 64; jb += 8) {
      float ev[8], xv[8];
#pragma unroll
      for (int u = 0; u < 8; ++u) ev[u] = ep[(jb + u) * 64];   // coalesced, batched
#pragma unroll
      for (int u = 0; u < 8; ++u) xv[u] = xp[(jb + u) * 64];
      const int j0 = w * 64 + jb;
#pragma unroll
      for (int h = 0; h < 8; ++h) {
        float4 pa = *(const float4*)&s_p[h * PSTR + j0];        // uniform -> broadcast
        float4 pb = *(const float4*)&s_p[h * PSTR + j0 + 4];
        ae[h] += pa.x * ev[0] + pa.y * ev[1] + pa.z * ev[2] + pa.w * ev[3]
               + pb.x * ev[4] + pb.y * ev[5] + pb.z * ev[6] + pb.w * ev[7];
        px[h] += pa.x * xv[0] + pa.y * xv[1] + pa.z * xv[2] + pa.w * xv[3]
               + pb.x * xv[4] + pb.y * xv[5] + pb.z * xv[6] + pb.w * xv[7];
      }
    }
#pragma unroll
    for (int h = 0; h < 8; ++h) {
      s_part[w * 1024 + h * 64 + lane] = ae[h];
      s_part[w * 1024 + 512 + h * 64 + lane] = px[h];
    }
  }
  __syncthreads();

  // reduce the 8 wave partials
  {
    float va = 0, vp = 0;
#pragma unroll
    for (int w = 0; w < 8; ++w) {
      va += s_part[w * 1024 + t];
      vp += s_part[w * 1024 + 512 + t];
    }
    s_ae[t] = va; s_px[t] = vp;
  }
  __syncthreads();

  // ---- Epilogue: emb[nd] = sum_c ae[n,c]We[c,nd] + px[n,c]Wv[c,nd]
  {
    const int nd = t & 255, ch = t >> 8, hn = nd >> 5;
    float emb = 0;
    const int cb = ch * 32;
#pragma unroll 8
    for (int c = cb; c < cb + 32; ++c)
      emb += s_ae[hn * 64 + c] * We[c * 256 + nd] + s_px[hn * 64 + c] * Wv[c * 256 + nd];
    s_part[ch * 256 + nd] = emb;
  }
  __syncthreads();
  if (t < 256) s_emb[t] = s_part[t] + s_part[256 + t];
  __syncthreads();
  // out[o] = sum_m emb[m]*Wo[m,o] + bo[o]
  {
    const int o = t & 63, mc = t >> 6;
    float oo = 0;
#pragma unroll 8
    for (int m2 = mc * 32; m2 < mc * 32 + 32; ++m2) oo += s_emb[m2] * Wo[m2 * 64 + o];
    s_op[mc * 64 + o] = oo;
  }
  __syncthreads();
  if (t < 64) {
    float r = bo[t];
#pragma unroll
    for (int w = 0; w < 8; ++w) r += s_op[w * 64 + t];
    out[i * 64 + t] = r;
  }
}

extern "C" void kernel_launch(void* const* d_in, const int* in_sizes, int n_in,
                              void* d_out, int out_size, void* d_ws, size_t ws_size,
                              hipStream_t stream) {
  const float* x  = (const float*)d_in[0];
  const float* e  = (const float*)d_in[1];
  const float* Wq = (const float*)d_in[2];
  const float* Wk = (const float*)d_in[3];
  const float* Wv = (const float*)d_in[4];
  const float* We = (const float*)d_in[5];
  const float* Wo = (const float*)d_in[6];
  const float* bo = (const float*)d_in[7];
  float* out = (float*)d_out;

  hipLaunchKernelGGL(fused_kernel, dim3(512), dim3(512), 0, stream,
                     e, x, Wq, Wk, We, Wv, Wo, bo, out);
}